// Round 4
// baseline (415.739 us; speedup 1.0000x reference)
//
#include <hip/hip_runtime.h>

// DoubleConv: hypernet 3x3 radius-interp conv x2 + per-item BN+ReLU.
// Round 4: dual-radius accumulators (raw weights, epilogue lerp),
// Bs staged via global_load_lds from pre-swizzled HBM layout, XCD-swizzled 1D grid.

#define SD 6
#define HD 128
#define HYPER_OUT 294912
#define BN_EPS 1e-5f

typedef unsigned short ushort_t;
typedef __attribute__((ext_vector_type(8))) short bf16x8;
typedef __attribute__((ext_vector_type(4))) float f32x4;

__device__ inline ushort_t f2bf(float f) {
  union { float f; unsigned u; } v; v.f = f;
  unsigned r = v.u + 0x7fffu + ((v.u >> 16) & 1u);   // RNE
  return (ushort_t)(r >> 16);
}
__device__ inline float bf2f(ushort_t h) {
  union { unsigned u; float f; } v; v.u = ((unsigned)h) << 16; return v.f;
}
__device__ inline unsigned pack2(float a, float b) {
  return (unsigned)f2bf(a) | ((unsigned)f2bf(b) << 16);
}

// async global->LDS, 16B per lane; LDS dest = wave-uniform base + lane*16
__device__ inline void gload16(const ushort_t* g, ushort_t* l) {
  __builtin_amdgcn_global_load_lds(
      (const __attribute__((address_space(1))) unsigned int*)(const void*)g,
      (__attribute__((address_space(3))) unsigned int*)(void*)l, 16, 0, 0);
}

// As element offset with XOR swizzle (16B-unit low-3 bits ^= row&7)
__device__ inline int as_off(int row, int cu) {    // As[130 rows][16 units of 8]
  return row*128 + ((cu ^ (row & 7)) << 3);
}

// ---------------- e-MLPs: e_all[16][128], row = item*8 + conv*4 + n ----------------
__global__ __launch_bounds__(128) void k_mlp(
    const float* __restrict__ seidel,
    const float* __restrict__ m1_w1, const float* __restrict__ m1_b1,
    const float* __restrict__ m1_w2, const float* __restrict__ m1_b2,
    const float* __restrict__ m2_w1, const float* __restrict__ m2_b1,
    const float* __restrict__ m2_w2, const float* __restrict__ m2_b2,
    float* __restrict__ e_all)
{
  int b = blockIdx.x;                 // 16 blocks
  int item = b >> 3, conv = (b >> 2) & 1, n = b & 3;
  const float* w1 = conv ? m2_w1 : m1_w1;
  const float* b1 = conv ? m2_b1 : m1_b1;
  const float* w2 = conv ? m2_w2 : m1_w2;
  const float* b2 = conv ? m2_b2 : m1_b2;
  int t = threadIdx.x;                // 128
  __shared__ float e1[HD];
  float s = b1[n*HD + t];
  #pragma unroll
  for (int i = 0; i < SD; ++i) s = fmaf(seidel[item*SD + i], w1[(n*SD + i)*HD + t], s);
  e1[t] = fmaxf(s, 0.f);
  __syncthreads();
  float s2 = b2[n*HD + t];
  for (int i = 0; i < HD; ++i) s2 = fmaf(e1[i], w2[(n*HD + i)*HD + t], s2);
  e_all[b*HD + t] = fmaxf(s2, 0.f);
}

// ---------------- hyper GEMM -> wb_lin[j][16] bf16 (coalesced writes) --------------
__global__ __launch_bounds__(256) void k_hyper(
    const float* __restrict__ e_all, const float* __restrict__ hyper_w,
    const float* __restrict__ hyper_b, ushort_t* __restrict__ wb_lin)
{
  __shared__ float es[16*HD];
  int t = threadIdx.x;
  for (int f = t; f < 16*HD; f += 256) es[f] = e_all[f];
  __syncthreads();
  int j = blockIdx.x*256 + t;         // 1152 * 256 = 294912
  float val[16];
  #pragma unroll
  for (int r = 0; r < 16; ++r) val[r] = 0.f;
  for (int i = 0; i < HD; ++i) {
    float hw = hyper_w[(size_t)i*HYPER_OUT + j];
    #pragma unroll
    for (int r = 0; r < 16; ++r) val[r] = fmaf(es[r*HD + i], hw, val[r]);
  }
  float bias = hyper_b[j];
  uint4 u0, u1;
  u0.x = pack2(val[0]+bias,  val[1]+bias);
  u0.y = pack2(val[2]+bias,  val[3]+bias);
  u0.z = pack2(val[4]+bias,  val[5]+bias);
  u0.w = pack2(val[6]+bias,  val[7]+bias);
  u1.x = pack2(val[8]+bias,  val[9]+bias);
  u1.y = pack2(val[10]+bias, val[11]+bias);
  u1.z = pack2(val[12]+bias, val[13]+bias);
  u1.w = pack2(val[14]+bias, val[15]+bias);
  *reinterpret_cast<uint4*>(wb_lin + (size_t)j*16)     = u0;
  *reinterpret_cast<uint4*>(wb_lin + (size_t)j*16 + 8) = u1;
}

// ---------------- repack wb_lin[j][16] -> wb2 pre-swizzled ----------------
// wb2 layout: [(conv*2+item)][nr][kj][ki][ch][o(128)][pu(8)*8], pu = cu ^ (o&7)
__global__ __launch_bounds__(256) void k_repack(
    const ushort_t* __restrict__ wb_lin, ushort_t* __restrict__ wb2)
{
  __shared__ ushort_t lds[16][256];
  int chunk = blockIdx.x;             // 0..15 (u-groups of 4)
  int tap   = blockIdx.y;             // 0..71
  int nr = tap / 9, kk = tap % 9;
  int ki = kk / 3, kj = kk % 3;
  int t = threadIdx.x;
  int uv = chunk*256 + t;             // u = uv>>6, v = uv&63
  size_t j = (size_t)uv*72 + nr*9 + kk;
  uint4 q0 = *reinterpret_cast<const uint4*>(wb_lin + j*16);
  uint4 q1 = *reinterpret_cast<const uint4*>(wb_lin + j*16 + 8);
  const ushort_t* pr0 = reinterpret_cast<const ushort_t*>(&q0);
  const ushort_t* pr1 = reinterpret_cast<const ushort_t*>(&q1);
  #pragma unroll
  for (int r = 0; r < 8; ++r) lds[r][t]     = pr0[r];
  #pragma unroll
  for (int r = 0; r < 8; ++r) lds[r + 8][t] = pr1[r];
  __syncthreads();
  #pragma unroll
  for (int it = 0; it < 2; ++it) {
    int idx = it*256 + t;             // 512 row-segments
    int row = idx >> 3, seg = idx & 7;
    int p = row >> 2, ul = row & 3;
    int item = p >> 3, conv = (p >> 2) & 1, n = p & 3;
    int o  = (n >> 1)*64 + chunk*4 + ul;
    int ch = n & 1;
    int pu = seg ^ (o & 7);
    uint4 v = *reinterpret_cast<const uint4*>(&lds[p][ul*64 + seg*8]);
    size_t slice = ((((size_t)(conv*2 + item)*8 + nr)*3 + kj)*3 + ki)*2 + ch;
    *reinterpret_cast<uint4*>(wb2 + (slice*128 + o)*64 + pu*8) = v;
  }
}

// ---------------- transpose x: [item][c][h][w] f32 -> [item][w][h][c] bf16 ----------
__global__ __launch_bounds__(256) void k_transpose(
    const float* __restrict__ x, ushort_t* __restrict__ xt)
{
  __shared__ float tile[64][65];      // [c][w]
  int wt = blockIdx.x, ct = blockIdx.y;
  int h = blockIdx.z & 255, item = blockIdx.z >> 8;
  int t = threadIdx.x;
  {
    int cl = t >> 2, wk = (t & 3) << 4;
    const float* sp = x + (((size_t)item*128 + ct*64 + cl)*256 + h)*256 + wt*64 + wk;
    #pragma unroll
    for (int k = 0; k < 16; k += 4) {
      float4 v = *reinterpret_cast<const float4*>(sp + k);
      tile[cl][wk+k] = v.x; tile[cl][wk+k+1] = v.y;
      tile[cl][wk+k+2] = v.z; tile[cl][wk+k+3] = v.w;
    }
  }
  __syncthreads();
  {
    int wl = t >> 2, ck = (t & 3) << 4;
    ushort_t* dp = xt + (((size_t)item*256 + wt*64 + wl)*256 + h)*128 + ct*64 + ck;
    uint4 u0, u1;
    u0.x = pack2(tile[ck+0][wl],  tile[ck+1][wl]);
    u0.y = pack2(tile[ck+2][wl],  tile[ck+3][wl]);
    u0.z = pack2(tile[ck+4][wl],  tile[ck+5][wl]);
    u0.w = pack2(tile[ck+6][wl],  tile[ck+7][wl]);
    u1.x = pack2(tile[ck+8][wl],  tile[ck+9][wl]);
    u1.y = pack2(tile[ck+10][wl], tile[ck+11][wl]);
    u1.z = pack2(tile[ck+12][wl], tile[ck+13][wl]);
    u1.w = pack2(tile[ck+14][wl], tile[ck+15][wl]);
    *reinterpret_cast<uint4*>(dp)     = u0;
    *reinterpret_cast<uint4*>(dp + 8) = u1;
  }
}

// ---------------- MFMA conv: dual-radius acc, raw weights via global_load_lds -------
// src [item][w][h][c] bf16 ; wb2 pre-swizzled (see k_repack)
// dst [item][w][h][o] bf16 pre-BN ; ps/p2 partials [1024][128]
// grid 1024x1 (XCD-swizzled; wgid = ((item*256+w)*2+hb)), 256 threads.
template<bool BN_IN>
__global__ __launch_bounds__(256, 2) void k_conv(
    const ushort_t* __restrict__ src, const ushort_t* __restrict__ wb2,
    const float* __restrict__ bn_a, const float* __restrict__ bn_c,
    ushort_t* __restrict__ dst, float* __restrict__ ps, float* __restrict__ p2)
{
  __shared__ __align__(16) ushort_t As[130*128];    // 33,280 B (swizzled)
  __shared__ __align__(16) ushort_t Bs[2*128*64];   // 32,768 B (linear; HBM pre-swz)
  __shared__ float sbn[256];
  int bid = blockIdx.x;
  int wgid = ((bid & 7) << 7) | (bid >> 3);          // XCD-contiguous, hb-pairs adjacent
  int item = wgid >> 9;
  int w    = (wgid >> 1) & 255;
  int hb   = wgid & 1;
  int t = threadIdx.x;
  int lane = t & 63, wid = t >> 6;
  int l15 = lane & 15, g = lane >> 4;
  int wm = wid >> 1, wn = wid & 1;
  int br = wid >> 1, bh = wid & 1;                   // Bs staging: radius / o-half

  float pos = fminf(fmaxf((w + 0.5f)*0.03125f - 0.5f, 0.f), 7.f);
  int i0 = (int)pos; float fr = pos - (float)i0; int i1 = min(i0 + 1, 7);

  if constexpr (BN_IN)
    sbn[t] = (t < 128) ? bn_a[item*128 + t] : bn_c[item*128 + (t - 128)];

  const ushort_t* wbi = wb2 + (size_t)item*1179648;  // 8*9*2*8192

  f32x4 acc[2][4][4];
  #pragma unroll
  for (int r = 0; r < 2; ++r)
    #pragma unroll
    for (int a = 0; a < 4; ++a)
      #pragma unroll
      for (int b = 0; b < 4; ++b)
        acc[r][a][b] = (f32x4){0.f, 0.f, 0.f, 0.f};

  for (int s = 0; s < 18; ++s) {                     // s = kj*6 + ki*2 + ch
    int kj = (s >= 12) ? 2 : (s >= 6) ? 1 : 0;
    int r6 = s - kj*6;
    int ki = r6 >> 1, ch = r6 & 1;

    if (r6 == 0) {
      __syncthreads();                               // prev MFMA readers of As done
      int wc = w + kj - 1;
      bool valid = (wc >= 0) && (wc < 256);
      const ushort_t* sb = src + ((size_t)item*256 + (valid ? wc : 0))*32768;
      for (int f = t; f < 2080; f += 256) {          // 130 rows x 16 units
        int row = f >> 4, cu = f & 15;
        uint4 v = make_uint4(0u, 0u, 0u, 0u);
        if (valid) {
          int hg = (hb*128 + row - 1) & 255;         // circular pad in H
          v = *reinterpret_cast<const uint4*>(sb + ((size_t)hg << 7) + (cu << 3));
          if constexpr (BN_IN) {
            ushort_t* pv = reinterpret_cast<ushort_t*>(&v);
            int c0 = cu << 3;
            #pragma unroll
            for (int jj = 0; jj < 8; ++jj) {
              float xv = bf2f(pv[jj]);
              xv = fmaxf(fmaf(sbn[c0 + jj], xv, sbn[128 + c0 + jj]), 0.f);
              pv[jj] = f2bf(xv);
            }
          }
        }
        *reinterpret_cast<uint4*>(&As[as_off(row, cu)]) = v;
      }
    }
    __syncthreads();                                 // As visible; prev Bs readers done
    {
      int nr = br ? i1 : i0;
      const ushort_t* gsrc = wbi
          + ((size_t)((nr*3 + kj)*3 + ki)*2 + ch)*8192 + bh*4096 + lane*8;
      ushort_t* lb = &Bs[br*8192 + bh*4096];         // wave-uniform LDS base
      #pragma unroll
      for (int k = 0; k < 8; ++k)
        gload16(gsrc + k*512, lb + k*512);
    }
    __syncthreads();                                 // Bs ready (vmcnt drained)
    #pragma unroll
    for (int ks = 0; ks < 2; ++ks) {
      bf16x8 bfr[4];
      #pragma unroll
      for (int nf = 0; nf < 4; ++nf)
        bfr[nf] = *reinterpret_cast<const bf16x8*>(
            &As[as_off(wn*64 + nf*16 + l15 + ki, ch*8 + ks*4 + g)]);
      #pragma unroll
      for (int r = 0; r < 2; ++r) {
        #pragma unroll
        for (int mf = 0; mf < 4; ++mf) {
          int o = wm*64 + mf*16 + l15;
          bf16x8 af = *reinterpret_cast<const bf16x8*>(
              &Bs[((r << 7) + o)*64 + (((ks*4 + g) ^ (o & 7)) << 3)]);
          #pragma unroll
          for (int nf = 0; nf < 4; ++nf)
            acc[r][mf][nf] = __builtin_amdgcn_mfma_f32_16x16x32_bf16(
                af, bfr[nf], acc[r][mf][nf], 0, 0, 0);
        }
      }
    }
  }

  // epilogue: lerp combine, store bf16 [h][o], BN partials
  float w1f = fr, w0f = 1.f - fr;
  ushort_t* yb = dst + (((size_t)item*256 + w)*256 + hb*128)*128;
  float ssum[4][4], s2sum[4][4];
  #pragma unroll
  for (int a = 0; a < 4; ++a)
    #pragma unroll
    for (int b = 0; b < 4; ++b) { ssum[a][b] = 0.f; s2sum[a][b] = 0.f; }
  #pragma unroll
  for (int mf = 0; mf < 4; ++mf) {
    #pragma unroll
    for (int nf = 0; nf < 4; ++nf) {
      float v[4];
      #pragma unroll
      for (int r4 = 0; r4 < 4; ++r4) {
        v[r4] = fmaf(w1f, acc[1][mf][nf][r4], w0f*acc[0][mf][nf][r4]);
        ssum[mf][r4] += v[r4];
        s2sum[mf][r4] = fmaf(v[r4], v[r4], s2sum[mf][r4]);
      }
      int h  = wn*64 + nf*16 + l15;
      int o0 = wm*64 + mf*16 + (g << 2);
      uint2 u; u.x = pack2(v[0], v[1]); u.y = pack2(v[2], v[3]);
      *reinterpret_cast<uint2*>(yb + (size_t)h*128 + o0) = u;
    }
  }
  #pragma unroll
  for (int mf = 0; mf < 4; ++mf)
    #pragma unroll
    for (int r4 = 0; r4 < 4; ++r4)
      #pragma unroll
      for (int m = 1; m < 16; m <<= 1) {
        ssum[mf][r4]  += __shfl_xor(ssum[mf][r4], m);
        s2sum[mf][r4] += __shfl_xor(s2sum[mf][r4], m);
      }
  __syncthreads();                                   // reuse As as scratch
  float* redS  = reinterpret_cast<float*>(As);       // [4 wave][64 o-local]
  float* redS2 = redS + 256;
  if (l15 == 0) {
    #pragma unroll
    for (int mf = 0; mf < 4; ++mf)
      #pragma unroll
      for (int r4 = 0; r4 < 4; ++r4) {
        int ol = mf*16 + (g << 2) + r4;
        redS [wid*64 + ol] = ssum[mf][r4];
        redS2[wid*64 + ol] = s2sum[mf][r4];
      }
  }
  __syncthreads();
  if (t < 128) {
    int o = t, wmS = o >> 6, ol = o & 63;
    float S  = redS [(wmS*2)*64 + ol] + redS [(wmS*2+1)*64 + ol];
    float S2 = redS2[(wmS*2)*64 + ol] + redS2[(wmS*2+1)*64 + ol];
    size_t bi = ((size_t)item*256 + w)*2 + hb;
    ps[bi*128 + o] = S;
    p2[bi*128 + o] = S2;
  }
}

// ---------------- reduce partials -> BN affine (a,c) ----------------
__global__ __launch_bounds__(256) void k_bnapply(
    const float* __restrict__ ps, const float* __restrict__ p2,
    const float* __restrict__ gamma, const float* __restrict__ beta,
    float* __restrict__ bn_a, float* __restrict__ bn_c)
{
  __shared__ float r1[256], r2s[256];
  int item = blockIdx.x;
  int t = threadIdx.x; int o = t & 127; int half = t >> 7;
  float s = 0.f, s2 = 0.f;
  for (int i = half*256; i < half*256 + 256; ++i) {
    size_t bi = (size_t)(item*512 + i)*128 + o;
    s += ps[bi]; s2 += p2[bi];
  }
  r1[t] = s; r2s[t] = s2;
  __syncthreads();
  if (t < 128) {
    s  = r1[t]  + r1[t + 128];
    s2 = r2s[t] + r2s[t + 128];
    float mu  = s  * (1.f/65536.f);
    float var = s2 * (1.f/65536.f) - mu*mu;
    float a = gamma[o] * rsqrtf(var + BN_EPS);
    bn_a[item*128 + o] = a;
    bn_c[item*128 + o] = beta[o] - a*mu;
  }
}

// ---------------- final: BN2+ReLU + transpose [item][w][h][o] bf16 -> NCHW f32 ------
__global__ __launch_bounds__(256) void k_final(
    const ushort_t* __restrict__ y, const float* __restrict__ bn_a,
    const float* __restrict__ bn_c, float* __restrict__ out)
{
  __shared__ float tile[64][65];      // [w][o]
  int wt = blockIdx.x, ot = blockIdx.y;
  int h = blockIdx.z & 255, item = blockIdx.z >> 8;
  int t = threadIdx.x;
  {
    int wl = t >> 2, ck = (t & 3) << 4;
    const ushort_t* sp = y + (((size_t)item*256 + wt*64 + wl)*256 + h)*128 + ot*64 + ck;
    uint4 a = *reinterpret_cast<const uint4*>(sp);
    uint4 b = *reinterpret_cast<const uint4*>(sp + 8);
    const ushort_t* pa = reinterpret_cast<const ushort_t*>(&a);
    const ushort_t* pb = reinterpret_cast<const ushort_t*>(&b);
    #pragma unroll
    for (int k = 0; k < 8; ++k) {
      int o = ot*64 + ck + k;
      tile[wl][ck + k] = fmaxf(fmaf(bn_a[item*128 + o], bf2f(pa[k]), bn_c[item*128 + o]), 0.f);
    }
    #pragma unroll
    for (int k = 0; k < 8; ++k) {
      int o = ot*64 + ck + 8 + k;
      tile[wl][ck + 8 + k] = fmaxf(fmaf(bn_a[item*128 + o], bf2f(pb[k]), bn_c[item*128 + o]), 0.f);
    }
  }
  __syncthreads();
  {
    int ol = t >> 2, wk = (t & 3) << 4;
    float* dp = out + (((size_t)item*128 + ot*64 + ol)*256 + h)*256 + wt*64 + wk;
    #pragma unroll
    for (int k = 0; k < 16; k += 4) {
      float4 v;
      v.x = tile[wk+k][ol];   v.y = tile[wk+k+1][ol];
      v.z = tile[wk+k+2][ol]; v.w = tile[wk+k+3][ol];
      *reinterpret_cast<float4*>(dp + k) = v;
    }
  }
}

extern "C" void kernel_launch(void* const* d_in, const int* in_sizes, int n_in,
                              void* d_out, int out_size, void* d_ws, size_t ws_size,
                              hipStream_t stream) {
  const float* x       = (const float*)d_in[0];
  const float* seidel  = (const float*)d_in[1];
  const float* m1_w1   = (const float*)d_in[2];
  const float* m1_b1   = (const float*)d_in[3];
  const float* m1_w2   = (const float*)d_in[4];
  const float* m1_b2   = (const float*)d_in[5];
  const float* m2_w1   = (const float*)d_in[6];
  const float* m2_b1   = (const float*)d_in[7];
  const float* m2_w2   = (const float*)d_in[8];
  const float* m2_b2   = (const float*)d_in[9];
  const float* hyper_w = (const float*)d_in[10];
  const float* hyper_b = (const float*)d_in[11];
  const float* bn1_g   = (const float*)d_in[12];
  const float* bn1_b   = (const float*)d_in[13];
  const float* bn2_g   = (const float*)d_in[14];
  const float* bn2_b   = (const float*)d_in[15];

  char* ws = (char*)d_ws;
  float*    e_all  = (float*)ws;                                    // 8,192
  ushort_t* wb_lin = (ushort_t*)(ws + 8192);                        // 9,437,184
  ushort_t* wb2    = (ushort_t*)(ws + 9445376);                     // 9,437,184
  ushort_t* xt     = (ushort_t*)(ws + 18882560);                    // 33,554,432
  ushort_t* y1     = (ushort_t*)(ws + 52436992);                    // 33,554,432
  ushort_t* y2     = (ushort_t*)(ws + 85991424);                    // 33,554,432
  float*    ps     = (float*)(ws + 119545856);                      // 524,288
  float*    p2     = (float*)(ws + 120070144);                      // 524,288
  float*    bnb    = (float*)(ws + 120594432);                      // 4 KB
  float* bn1_a = bnb,        *bn1_c = bnb + 256;
  float* bn2_a = bnb + 512,  *bn2_c = bnb + 768;

  k_mlp<<<16, 128, 0, stream>>>(seidel, m1_w1, m1_b1, m1_w2, m1_b2,
                                m2_w1, m2_b1, m2_w2, m2_b2, e_all);
  k_hyper<<<HYPER_OUT/256, 256, 0, stream>>>(e_all, hyper_w, hyper_b, wb_lin);
  k_repack<<<dim3(16, 72), 256, 0, stream>>>(wb_lin, wb2);
  k_transpose<<<dim3(4, 2, 512), 256, 0, stream>>>(x, xt);

  k_conv<false><<<1024, 256, 0, stream>>>(xt, wb2, nullptr, nullptr, y1, ps, p2);
  k_bnapply<<<2, 256, 0, stream>>>(ps, p2, bn1_g, bn1_b, bn1_a, bn1_c);

  k_conv<true><<<1024, 256, 0, stream>>>(y1, wb2 + 2359296, bn1_a, bn1_c, y2, ps, p2);
  k_bnapply<<<2, 256, 0, stream>>>(ps, p2, bn2_g, bn2_b, bn2_a, bn2_c);
  k_final<<<dim3(4, 2, 512), 256, 0, stream>>>(y2, bn2_a, bn2_c, (float*)d_out);
}